// Round 1
// baseline (840.614 us; speedup 1.0000x reference)
//
#include <hip/hip_runtime.h>

// Problem: B=8, S=2048, D=1024, banded attention with window +-20.
// out[b,q,:] = softmax_k( q_{b,q}^T W key_{b,k} ,  |q-k|<=20 ) @ keys
// Bias b_reduce adds a per-q constant to all logits of a row -> cancels in
// softmax -> never computed.
// Out-of-band logits get -1e8 -> exp underflows to exactly 0 in f32 -> only
// the <=41 in-band keys participate.

#define BATCH 8
#define SEQ   2048
#define DIM   1024
#define WIN   20

// ---------------------------------------------------------------------------
// Kernel 1: qt = Q @ W   (M=B*S=16384, N=K=1024), fp32, written into d_out.
// 128x128 tile, BK=8, 256 threads, 8x8 acc per thread.
// ---------------------------------------------------------------------------
__global__ __launch_bounds__(256) void gemm_qw(const float* __restrict__ Q,
                                               const float* __restrict__ W,
                                               float* __restrict__ QT) {
    const int N = DIM, K = DIM;
    __shared__ float As[8][132];   // As[k][m], pad 132 keeps 16B align + no store conflicts
    __shared__ float Bs[8][128];   // Bs[k][n]

    const int bm = blockIdx.y;     // 0..127
    const int bn = blockIdx.x;     // 0..7
    const int t  = threadIdx.x;

    // A staging: thread t loads A[bm*128 + t/2][k0 + (t&1)*4 .. +3]
    const int a_row  = t >> 1;
    const int a_col4 = (t & 1) * 4;
    // B staging: thread t loads B[k0 + t/32][bn*128 + (t&31)*4 .. +3]
    const int b_row  = t >> 5;
    const int b_col4 = (t & 31) * 4;

    const int tx = t & 15, ty = t >> 4;

    const float* Aptr = Q + (size_t)(bm * 128 + a_row) * K + a_col4;
    const float* Bptr = W + (size_t)b_row * N + bn * 128 + b_col4;

    float acc[8][8] = {};

    for (int k0 = 0; k0 < K; k0 += 8) {
        float4 av = *(const float4*)(Aptr + k0);
        float4 bv = *(const float4*)(Bptr + (size_t)k0 * N);

        As[a_col4 + 0][a_row] = av.x;
        As[a_col4 + 1][a_row] = av.y;
        As[a_col4 + 2][a_row] = av.z;
        As[a_col4 + 3][a_row] = av.w;
        *(float4*)&Bs[b_row][b_col4] = bv;
        __syncthreads();

        #pragma unroll
        for (int kk = 0; kk < 8; ++kk) {
            float4 a0 = *(const float4*)&As[kk][ty * 8];
            float4 a1 = *(const float4*)&As[kk][ty * 8 + 4];
            float4 b0 = *(const float4*)&Bs[kk][tx * 8];
            float4 b1 = *(const float4*)&Bs[kk][tx * 8 + 4];
            float a[8]  = {a0.x, a0.y, a0.z, a0.w, a1.x, a1.y, a1.z, a1.w};
            float bb[8] = {b0.x, b0.y, b0.z, b0.w, b1.x, b1.y, b1.z, b1.w};
            #pragma unroll
            for (int i = 0; i < 8; ++i)
                #pragma unroll
                for (int j = 0; j < 8; ++j)
                    acc[i][j] = fmaf(a[i], bb[j], acc[i][j]);
        }
        __syncthreads();
    }

    // Write C tile
    #pragma unroll
    for (int i = 0; i < 8; ++i) {
        float* crow = QT + (size_t)(bm * 128 + ty * 8 + i) * N + bn * 128 + tx * 8;
        float4 c0 = {acc[i][0], acc[i][1], acc[i][2], acc[i][3]};
        float4 c1 = {acc[i][4], acc[i][5], acc[i][6], acc[i][7]};
        *(float4*)(crow)     = c0;
        *(float4*)(crow + 4) = c1;
    }
}

// ---------------------------------------------------------------------------
// Kernel 2: banded softmax-attention, in place on d_out.
// One block (256 thr) per (b,q). Reads its own qt row into LDS, computes
// <=41 in-band logits, softmax, then overwrites the row with weights @ keys.
// ---------------------------------------------------------------------------
__global__ __launch_bounds__(256) void attn_band(const float* __restrict__ QT,
                                                 const float* __restrict__ Keys,
                                                 float* __restrict__ Out) {
    const int q = blockIdx.x;
    const int b = blockIdx.y;
    const int t = threadIdx.x;

    const float* qt   = QT + ((size_t)b * SEQ + q) * DIM;
    const float* keys = Keys + (size_t)b * SEQ * DIM;

    const int klo = (q - WIN) > 0 ? (q - WIN) : 0;
    const int khi = (q + WIN) < (SEQ - 1) ? (q + WIN) : (SEQ - 1);
    const int nk  = khi - klo + 1;   // <= 41

    __shared__ float qs[DIM];
    __shared__ float sa[64];
    __shared__ float wa[64];

    #pragma unroll
    for (int i = 0; i < DIM / 256; ++i) qs[t + 256 * i] = qt[t + 256 * i];
    __syncthreads();

    const int wave = t >> 6, lane = t & 63;

    // Phase 1: logits. Wave w handles k-offsets w, w+4, w+8, ...
    for (int kk = wave; kk < nk; kk += 4) {
        const float* krow = keys + (size_t)(klo + kk) * DIM;
        float p = 0.f;
        #pragma unroll
        for (int i = 0; i < DIM / 64; ++i)
            p = fmaf(qs[lane + 64 * i], krow[lane + 64 * i], p);
        #pragma unroll
        for (int off = 32; off > 0; off >>= 1) p += __shfl_down(p, off);
        if (lane == 0) sa[kk] = p;
    }
    __syncthreads();

    // Phase 2: softmax over nk logits (redundant per thread, deterministic).
    float m = -1e30f;
    for (int kk = 0; kk < nk; ++kk) m = fmaxf(m, sa[kk]);
    float sum = 0.f;
    for (int kk = 0; kk < nk; ++kk) sum += expf(sa[kk] - m);
    const float inv = 1.f / sum;
    if (t < nk) wa[t] = expf(sa[t] - m) * inv;
    __syncthreads();

    // Phase 3: out = weights @ keys, coalesced, in place.
    float acc0 = 0.f, acc1 = 0.f, acc2 = 0.f, acc3 = 0.f;
    for (int kk = 0; kk < nk; ++kk) {
        const float w = wa[kk];
        const float* krow = keys + (size_t)(klo + kk) * DIM;
        acc0 = fmaf(w, krow[t],       acc0);
        acc1 = fmaf(w, krow[t + 256], acc1);
        acc2 = fmaf(w, krow[t + 512], acc2);
        acc3 = fmaf(w, krow[t + 768], acc3);
    }
    float* o = Out + ((size_t)b * SEQ + q) * DIM;
    o[t]       = acc0;
    o[t + 256] = acc1;
    o[t + 512] = acc2;
    o[t + 768] = acc3;
}

extern "C" void kernel_launch(void* const* d_in, const int* in_sizes, int n_in,
                              void* d_out, int out_size, void* d_ws, size_t ws_size,
                              hipStream_t stream) {
    const float* queries = (const float*)d_in[0];
    const float* keys    = (const float*)d_in[1];
    const float* W       = (const float*)d_in[2];
    // d_in[3] (b_reduce) intentionally unused: constant over k, cancels in softmax.
    float* out = (float*)d_out;

    dim3 g1(DIM / 128, (BATCH * SEQ) / 128);   // (8, 128)
    gemm_qw<<<g1, 256, 0, stream>>>(queries, W, out);

    dim3 g2(SEQ, BATCH);                        // (2048, 8)
    attn_band<<<g2, 256, 0, stream>>>(out, keys, out);
}

// Round 2
// 531.371 us; speedup vs baseline: 1.5820x; 1.5820x over previous
//
#include <hip/hip_runtime.h>

// B=8, S=2048, D=1024 banded attention, window +-20.
// out[b,q,:] = softmax_k( q^T W key_k , |q-k|<=20 ) @ keys
// b_reduce adds a per-q constant to every logit of a row -> cancels in softmax.
// -1e8 mask -> out-of-band weights are exactly 0 -> only <=41 keys per row.
//
// R2: qt = Q@W moved to f16 MFMA (fp32 accumulate). f16 (not bf16) keeps the
// logit error ~0.009 abs (bf16 would be ~0.07 -> softmax tie-amplification
// risk vs 0.108 absmax threshold).

#define BATCH 8
#define SEQ   2048
#define DIM   1024
#define WIN   20

typedef _Float16 half8 __attribute__((ext_vector_type(8)));
typedef float    f32x4 __attribute__((ext_vector_type(4)));

#define LDK 40   // padded K-stride (f16 units): 80 B = 5*16 -> b128-aligned, 2-way-free banks

// ---------------------------------------------------------------------------
// Kernel 1: qt = Q @ W  (M=16384, N=K=1024), f16 MFMA, fp32 out into d_out.
// 128x128 block tile, BK=32, 256 threads = 4 waves in 2x2, each wave 64x64
// (4x4 grid of 16x16x32 MFMA tiles).
// Grid: x = M-tile (128), y = N-tile (8) -> linear%8 == Mtile%8, so all 8
// N-tiles sharing an A-tile land on the same XCD (L2 A-reuse); all 1024
// blocks are co-resident anyway (4 blocks/CU x 256 CU).
// ---------------------------------------------------------------------------
__global__ __launch_bounds__(256) void gemm_qw_f16(const float* __restrict__ Q,
                                                   const float* __restrict__ W,
                                                   float* __restrict__ QT) {
    __shared__ _Float16 Asl[128 * LDK];   // A[m][k], 10 KB
    __shared__ _Float16 Bsl[128 * LDK];   // B^T[n][k], 10 KB

    const int m0 = blockIdx.x * 128;
    const int n0 = blockIdx.y * 128;
    const int t  = threadIdx.x;
    const int lane = t & 63;
    const int wv   = t >> 6;             // wave 0..3
    const int wm   = (wv >> 1) * 64;     // wave row offset
    const int wn   = (wv & 1) * 64;      // wave col offset
    const int l15  = lane & 15;
    const int quad = lane >> 4;

    // A staging: row ar (2 threads/row), cols ac..ac+15 (4 float4 loads)
    const int ar = t >> 1;
    const int ac = (t & 1) * 16;
    const float* Aptr = Q + (size_t)(m0 + ar) * DIM + ac;
    _Float16* AsW = &Asl[ar * LDK + ac];

    // B staging w/ transpose: row br (0..31), cols bc+8j (stride-8 scatter ->
    // ds_write_b16 banks = 8 groups of 4 spanning all 32 -> 2-way alias, free)
    const int br = t >> 3;
    const int bc = t & 7;
    const float* Bptr = W + (size_t)br * DIM + n0 + bc;

    f32x4 acc[4][4] = {};

    for (int k0 = 0; k0 < DIM; k0 += 32) {
        float4 a0 = *(const float4*)(Aptr + k0);
        float4 a1 = *(const float4*)(Aptr + k0 + 4);
        float4 a2 = *(const float4*)(Aptr + k0 + 8);
        float4 a3 = *(const float4*)(Aptr + k0 + 12);
        float bv[16];
        #pragma unroll
        for (int j = 0; j < 16; ++j) bv[j] = Bptr[(size_t)k0 * DIM + 8 * j];

        __syncthreads();   // previous iteration's fragment reads done

        half8 h0, h1;
        h0[0] = (_Float16)a0.x; h0[1] = (_Float16)a0.y; h0[2] = (_Float16)a0.z; h0[3] = (_Float16)a0.w;
        h0[4] = (_Float16)a1.x; h0[5] = (_Float16)a1.y; h0[6] = (_Float16)a1.z; h0[7] = (_Float16)a1.w;
        h1[0] = (_Float16)a2.x; h1[1] = (_Float16)a2.y; h1[2] = (_Float16)a2.z; h1[3] = (_Float16)a2.w;
        h1[4] = (_Float16)a3.x; h1[5] = (_Float16)a3.y; h1[6] = (_Float16)a3.z; h1[7] = (_Float16)a3.w;
        *(half8*)(AsW)     = h0;     // 16B-aligned: ar*80 + ac*2
        *(half8*)(AsW + 8) = h1;

        #pragma unroll
        for (int j = 0; j < 16; ++j)
            Bsl[(bc + 8 * j) * LDK + br] = (_Float16)bv[j];

        __syncthreads();

        half8 af[4], bf[4];
        #pragma unroll
        for (int i = 0; i < 4; ++i)
            af[i] = *(const half8*)&Asl[(wm + i * 16 + l15) * LDK + quad * 8];
        #pragma unroll
        for (int j = 0; j < 4; ++j)
            bf[j] = *(const half8*)&Bsl[(wn + j * 16 + l15) * LDK + quad * 8];

        #pragma unroll
        for (int i = 0; i < 4; ++i)
            #pragma unroll
            for (int j = 0; j < 4; ++j)
                acc[i][j] = __builtin_amdgcn_mfma_f32_16x16x32_f16(af[i], bf[j], acc[i][j], 0, 0, 0);
    }

    // C/D layout: col = lane&15, row = quad*4 + reg  [m89-verified]
    #pragma unroll
    for (int i = 0; i < 4; ++i) {
        const int row0 = m0 + wm + i * 16 + quad * 4;
        #pragma unroll
        for (int r = 0; r < 4; ++r) {
            float* orow = QT + (size_t)(row0 + r) * DIM + n0 + wn + l15;
            #pragma unroll
            for (int j = 0; j < 4; ++j)
                orow[j * 16] = acc[i][j][r];
        }
    }
}

// ---------------------------------------------------------------------------
// Kernel 2: banded softmax-attention, in place on d_out (unchanged from R1).
// ---------------------------------------------------------------------------
__global__ __launch_bounds__(256) void attn_band(const float* __restrict__ QT,
                                                 const float* __restrict__ Keys,
                                                 float* __restrict__ Out) {
    const int q = blockIdx.x;
    const int b = blockIdx.y;
    const int t = threadIdx.x;

    const float* qt   = QT + ((size_t)b * SEQ + q) * DIM;
    const float* keys = Keys + (size_t)b * SEQ * DIM;

    const int klo = (q - WIN) > 0 ? (q - WIN) : 0;
    const int khi = (q + WIN) < (SEQ - 1) ? (q + WIN) : (SEQ - 1);
    const int nk  = khi - klo + 1;   // <= 41

    __shared__ float qs[DIM];
    __shared__ float sa[64];
    __shared__ float wa[64];

    #pragma unroll
    for (int i = 0; i < DIM / 256; ++i) qs[t + 256 * i] = qt[t + 256 * i];
    __syncthreads();

    const int wave = t >> 6, lane = t & 63;

    for (int kk = wave; kk < nk; kk += 4) {
        const float* krow = keys + (size_t)(klo + kk) * DIM;
        float p = 0.f;
        #pragma unroll
        for (int i = 0; i < DIM / 64; ++i)
            p = fmaf(qs[lane + 64 * i], krow[lane + 64 * i], p);
        #pragma unroll
        for (int off = 32; off > 0; off >>= 1) p += __shfl_down(p, off);
        if (lane == 0) sa[kk] = p;
    }
    __syncthreads();

    float m = -1e30f;
    for (int kk = 0; kk < nk; ++kk) m = fmaxf(m, sa[kk]);
    float sum = 0.f;
    for (int kk = 0; kk < nk; ++kk) sum += expf(sa[kk] - m);
    const float inv = 1.f / sum;
    if (t < nk) wa[t] = expf(sa[t] - m) * inv;
    __syncthreads();

    float acc0 = 0.f, acc1 = 0.f, acc2 = 0.f, acc3 = 0.f;
    for (int kk = 0; kk < nk; ++kk) {
        const float w = wa[kk];
        const float* krow = keys + (size_t)(klo + kk) * DIM;
        acc0 = fmaf(w, krow[t],       acc0);
        acc1 = fmaf(w, krow[t + 256], acc1);
        acc2 = fmaf(w, krow[t + 512], acc2);
        acc3 = fmaf(w, krow[t + 768], acc3);
    }
    float* o = Out + ((size_t)b * SEQ + q) * DIM;
    o[t]       = acc0;
    o[t + 256] = acc1;
    o[t + 512] = acc2;
    o[t + 768] = acc3;
}

extern "C" void kernel_launch(void* const* d_in, const int* in_sizes, int n_in,
                              void* d_out, int out_size, void* d_ws, size_t ws_size,
                              hipStream_t stream) {
    const float* queries = (const float*)d_in[0];
    const float* keys    = (const float*)d_in[1];
    const float* W       = (const float*)d_in[2];
    // d_in[3] (b_reduce): constant over k within a row -> cancels in softmax.
    float* out = (float*)d_out;

    dim3 g1(128, 8);            // x = M-tile, y = N-tile (XCD-aware A-sharing)
    gemm_qw_f16<<<g1, 256, 0, stream>>>(queries, W, out);

    dim3 g2(SEQ, BATCH);
    attn_band<<<g2, 256, 0, stream>>>(out, keys, out);
}

// Round 3
// 286.267 us; speedup vs baseline: 2.9365x; 1.8562x over previous
//
#include <hip/hip_runtime.h>

// B=8, S=2048, D=1024 banded attention, window +-20.
// out[b,q,:] = softmax_k( q^T W key_k , |q-k|<=20 ) @ keys
// b_reduce: per-q constant on every logit -> cancels in softmax -> unused.
// -1e8 mask -> out-of-band weights exactly 0 -> only <=41 keys per row.
//
// R3: attn rewritten: 16 queries/block (union window 56 keys, padded 64),
// QK^T via f16 MFMA, softmax in-block, PV as fp32 vector FMA.
// Linear grid with b = blk&7 pins each batch to one XCD (keys L2-local).

#define BATCH 8
#define SEQ   2048
#define DIM   1024
#define WIN   20

typedef _Float16 half8 __attribute__((ext_vector_type(8)));
typedef _Float16 half4v __attribute__((ext_vector_type(4)));
typedef float    f32x4 __attribute__((ext_vector_type(4)));

#define LDK 40   // gemm LDS K-stride (f16): 80 B = 5*16 -> b128-aligned

// ---------------------------------------------------------------------------
// Kernel 1: qt = Q @ W  (M=16384, N=K=1024), f16 MFMA, fp32 out into d_out.
// (unchanged from R2 — known good, ~200 us; next round's target)
// ---------------------------------------------------------------------------
__global__ __launch_bounds__(256) void gemm_qw_f16(const float* __restrict__ Q,
                                                   const float* __restrict__ W,
                                                   float* __restrict__ QT) {
    __shared__ _Float16 Asl[128 * LDK];
    __shared__ _Float16 Bsl[128 * LDK];

    const int m0 = blockIdx.x * 128;
    const int n0 = blockIdx.y * 128;
    const int t  = threadIdx.x;
    const int lane = t & 63;
    const int wv   = t >> 6;
    const int wm   = (wv >> 1) * 64;
    const int wn   = (wv & 1) * 64;
    const int l15  = lane & 15;
    const int quad = lane >> 4;

    const int ar = t >> 1;
    const int ac = (t & 1) * 16;
    const float* Aptr = Q + (size_t)(m0 + ar) * DIM + ac;
    _Float16* AsW = &Asl[ar * LDK + ac];

    const int br = t >> 3;
    const int bc = t & 7;
    const float* Bptr = W + (size_t)br * DIM + n0 + bc;

    f32x4 acc[4][4] = {};

    for (int k0 = 0; k0 < DIM; k0 += 32) {
        float4 a0 = *(const float4*)(Aptr + k0);
        float4 a1 = *(const float4*)(Aptr + k0 + 4);
        float4 a2 = *(const float4*)(Aptr + k0 + 8);
        float4 a3 = *(const float4*)(Aptr + k0 + 12);
        float bv[16];
        #pragma unroll
        for (int j = 0; j < 16; ++j) bv[j] = Bptr[(size_t)k0 * DIM + 8 * j];

        __syncthreads();

        half8 h0, h1;
        h0[0] = (_Float16)a0.x; h0[1] = (_Float16)a0.y; h0[2] = (_Float16)a0.z; h0[3] = (_Float16)a0.w;
        h0[4] = (_Float16)a1.x; h0[5] = (_Float16)a1.y; h0[6] = (_Float16)a1.z; h0[7] = (_Float16)a1.w;
        h1[0] = (_Float16)a2.x; h1[1] = (_Float16)a2.y; h1[2] = (_Float16)a2.z; h1[3] = (_Float16)a2.w;
        h1[4] = (_Float16)a3.x; h1[5] = (_Float16)a3.y; h1[6] = (_Float16)a3.z; h1[7] = (_Float16)a3.w;
        *(half8*)(AsW)     = h0;
        *(half8*)(AsW + 8) = h1;

        #pragma unroll
        for (int j = 0; j < 16; ++j)
            Bsl[(bc + 8 * j) * LDK + br] = (_Float16)bv[j];

        __syncthreads();

        half8 af[4], bf[4];
        #pragma unroll
        for (int i = 0; i < 4; ++i)
            af[i] = *(const half8*)&Asl[(wm + i * 16 + l15) * LDK + quad * 8];
        #pragma unroll
        for (int j = 0; j < 4; ++j)
            bf[j] = *(const half8*)&Bsl[(wn + j * 16 + l15) * LDK + quad * 8];

        #pragma unroll
        for (int i = 0; i < 4; ++i)
            #pragma unroll
            for (int j = 0; j < 4; ++j)
                acc[i][j] = __builtin_amdgcn_mfma_f32_16x16x32_f16(af[i], bf[j], acc[i][j], 0, 0, 0);
    }

    #pragma unroll
    for (int i = 0; i < 4; ++i) {
        const int row0 = m0 + wm + i * 16 + quad * 4;
        #pragma unroll
        for (int r = 0; r < 4; ++r) {
            float* orow = QT + (size_t)(row0 + r) * DIM + n0 + wn + l15;
            #pragma unroll
            for (int j = 0; j < 4; ++j)
                orow[j * 16] = acc[i][j][r];
        }
    }
}

// ---------------------------------------------------------------------------
// Kernel 2: banded attention, 16 queries per block, in place on d_out.
//  - union key window: klo..khi, nk<=56, padded to 64 MFMA columns
//  - QK^T: f16 MFMA 16x16x32 over D; wave w owns key cols [16w,16w+16)
//  - softmax by wave 0 (4 lanes per q-row)
//  - PV: fp32 vector FMA, keys re-read from global (L2-hot, XCD-pinned)
// In-place safe: block only reads its own 16 qt rows, then overwrites them.
// ---------------------------------------------------------------------------
#define TQ  16
#define KP  64
#define KLD 80   // Ks stride (f16): mult of 8 (b128 align), 4-way banks max
#define QLD 80
#define SLD 66   // Sl/Wl stride (f32)

__global__ __launch_bounds__(256, 4) void attn_mfma(const float* __restrict__ QT,
                                                    const float* __restrict__ Keys,
                                                    float* __restrict__ Out) {
    const int blk  = blockIdx.x;
    const int b    = blk & 7;          // batch == XCD (8 XCDs): keys stay L2-local
    const int tile = blk >> 3;
    const int q0   = tile * TQ;
    const int t    = threadIdx.x;
    const int lane = t & 63;
    const int wv   = t >> 6;
    const int l15  = lane & 15;
    const int quad = lane >> 4;

    const int klo = (q0 - WIN) > 0 ? (q0 - WIN) : 0;
    const int khi = (q0 + TQ - 1 + WIN) < (SEQ - 1) ? (q0 + TQ - 1 + WIN) : (SEQ - 1);
    const int nk  = khi - klo + 1;     // <= 56

    const float* qt   = QT + ((size_t)b * SEQ + q0) * DIM;
    const float* keys = Keys + (size_t)b * SEQ * DIM;

    __shared__ _Float16 Qc[TQ * QLD];
    __shared__ _Float16 Ks[KP * KLD];
    __shared__ float    Sl[TQ * SLD];
    __shared__ float    Wl[TQ * SLD];

    // staging assignments
    const int qr = t >> 4;             // 0..15 (q row)
    const int qc = (t & 15) * 4;       // 0..60
    const int kr = t >> 2;             // 0..63 (key row)
    const int kc = (t & 3) * 4;        // 0,4,8,12
    const int krow = (klo + kr) < (SEQ - 1) ? (klo + kr) : (SEQ - 1);  // clamp pad rows

    const float* qsrc = qt + (size_t)qr * DIM + qc;
    const float* ksrc = keys + (size_t)krow * DIM + kc;

    f32x4 acc_s = {};   // this wave's 16x16 logit tile

    for (int d0 = 0; d0 < DIM; d0 += 64) {
        float4 qv  = *(const float4*)(qsrc + d0);
        float4 kv0 = *(const float4*)(ksrc + d0);
        float4 kv1 = *(const float4*)(ksrc + d0 + 16);
        float4 kv2 = *(const float4*)(ksrc + d0 + 32);
        float4 kv3 = *(const float4*)(ksrc + d0 + 48);

        __syncthreads();   // previous iteration's fragment reads done

        half4v hq = {(_Float16)qv.x, (_Float16)qv.y, (_Float16)qv.z, (_Float16)qv.w};
        *(half4v*)&Qc[qr * QLD + qc] = hq;
        half4v h0 = {(_Float16)kv0.x, (_Float16)kv0.y, (_Float16)kv0.z, (_Float16)kv0.w};
        half4v h1 = {(_Float16)kv1.x, (_Float16)kv1.y, (_Float16)kv1.z, (_Float16)kv1.w};
        half4v h2 = {(_Float16)kv2.x, (_Float16)kv2.y, (_Float16)kv2.z, (_Float16)kv2.w};
        half4v h3 = {(_Float16)kv3.x, (_Float16)kv3.y, (_Float16)kv3.z, (_Float16)kv3.w};
        *(half4v*)&Ks[kr * KLD + kc]      = h0;
        *(half4v*)&Ks[kr * KLD + kc + 16] = h1;
        *(half4v*)&Ks[kr * KLD + kc + 32] = h2;
        *(half4v*)&Ks[kr * KLD + kc + 48] = h3;

        __syncthreads();

        #pragma unroll
        for (int s = 0; s < 2; ++s) {
            half8 af = *(const half8*)&Qc[l15 * QLD + s * 32 + quad * 8];
            half8 bf = *(const half8*)&Ks[(wv * 16 + l15) * KLD + s * 32 + quad * 8];
            acc_s = __builtin_amdgcn_mfma_f32_16x16x32_f16(af, bf, acc_s, 0, 0, 0);
        }
    }

    // logits -> Sl with band mask. C layout: col=lane&15 (key), row=quad*4+reg (q).
    __syncthreads();
    #pragma unroll
    for (int r = 0; r < 4; ++r) {
        const int q = quad * 4 + r;
        const int c = wv * 16 + l15;
        const int d = (q0 + q) - (klo + c);
        const bool valid = (c < nk) && ((unsigned)(d + WIN) <= 2u * WIN);
        Sl[q * SLD + c] = valid ? acc_s[r] : -1e30f;
    }
    __syncthreads();

    // softmax: wave 0, 4 lanes per q-row, 16 cols per lane
    if (t < 64) {
        const int q = t >> 2, part = t & 3;
        const float* srow = &Sl[q * SLD + part * 16];
        float*       wrow = &Wl[q * SLD + part * 16];
        float m = -1e30f;
        #pragma unroll
        for (int i = 0; i < 16; ++i) m = fmaxf(m, srow[i]);
        m = fmaxf(m, __shfl_xor(m, 1));
        m = fmaxf(m, __shfl_xor(m, 2));
        float ssum = 0.f;
        #pragma unroll
        for (int i = 0; i < 16; ++i) { float e = expf(srow[i] - m); wrow[i] = e; ssum += e; }
        ssum += __shfl_xor(ssum, 1);
        ssum += __shfl_xor(ssum, 2);
        const float inv = 1.f / ssum;
        #pragma unroll
        for (int i = 0; i < 16; ++i) wrow[i] *= inv;
    }
    __syncthreads();

    // PV: thread t owns d-cols {t, t+256, t+512, t+768}; fp32 keys from global.
    float accs[TQ][4] = {};
    for (int c = 0; c < nk; ++c) {
        const float* krow2 = keys + (size_t)(klo + c) * DIM;
        const float k0 = krow2[t], k1 = krow2[t + 256], k2 = krow2[t + 512], k3 = krow2[t + 768];
        #pragma unroll
        for (int q = 0; q < TQ; ++q) {
            const float w = Wl[q * SLD + c];   // same addr across lanes: broadcast
            accs[q][0] = fmaf(w, k0, accs[q][0]);
            accs[q][1] = fmaf(w, k1, accs[q][1]);
            accs[q][2] = fmaf(w, k2, accs[q][2]);
            accs[q][3] = fmaf(w, k3, accs[q][3]);
        }
    }
    #pragma unroll
    for (int q = 0; q < TQ; ++q) {
        float* orow = Out + ((size_t)b * SEQ + q0 + q) * DIM;
        orow[t]       = accs[q][0];
        orow[t + 256] = accs[q][1];
        orow[t + 512] = accs[q][2];
        orow[t + 768] = accs[q][3];
    }
}

extern "C" void kernel_launch(void* const* d_in, const int* in_sizes, int n_in,
                              void* d_out, int out_size, void* d_ws, size_t ws_size,
                              hipStream_t stream) {
    const float* queries = (const float*)d_in[0];
    const float* keys    = (const float*)d_in[1];
    const float* W       = (const float*)d_in[2];
    // d_in[3] (b_reduce): constant over k within a row -> cancels in softmax.
    float* out = (float*)d_out;

    dim3 g1(128, 8);
    gemm_qw_f16<<<g1, 256, 0, stream>>>(queries, W, out);

    const int nblk = (BATCH * SEQ) / TQ;   // 1024
    attn_mfma<<<nblk, 256, 0, stream>>>(out, keys, out);
}